// Round 5
// baseline (431.277 us; speedup 1.0000x reference)
//
#include <hip/hip_runtime.h>
#include <math.h>

#define SDE_B 16384
#define SDE_S 16
#define SDE_STEPS 50
#define SDE_L 128
#define SDE_DT 0.02f
#define SDE_SQRT_DT 0.14142135623730951f
#define SDE_TEMP 20.0f
#define LOG2E 1.44269504088896340736f
#define LN2 0.69314718055994530942f

typedef float f2 __attribute__((ext_vector_type(2)));

#if __has_builtin(__builtin_amdgcn_exp2f)
__device__ __forceinline__ float fexp2(float x) { return __builtin_amdgcn_exp2f(x); }
#else
__device__ __forceinline__ float fexp2(float x) { return __exp2f(x); }
#endif

#if __has_builtin(__builtin_amdgcn_logf)
__device__ __forceinline__ float flog2(float x) { return __builtin_amdgcn_logf(x); }
#else
__device__ __forceinline__ float flog2(float x) { return __log2f(x); }
#endif

#if __has_builtin(__builtin_amdgcn_rcpf)
__device__ __forceinline__ float frcp(float x) { return __builtin_amdgcn_rcpf(x); }
#else
__device__ __forceinline__ float frcp(float x) { return 1.0f / x; }
#endif

__device__ __forceinline__ f2 ffma2(f2 a, f2 b, f2 c) {
#if __has_builtin(__builtin_elementwise_fma)
    return __builtin_elementwise_fma(a, b, c);
#else
    return (f2){fmaf(a.x, b.x, c.x), fmaf(a.y, b.y, c.y)};
#endif
}
__device__ __forceinline__ f2 fclamp2(f2 v, float lo, float hi) {
#if __has_builtin(__builtin_elementwise_min) && __has_builtin(__builtin_elementwise_max)
    return __builtin_elementwise_min(__builtin_elementwise_max(v, (f2){lo, lo}), (f2){hi, hi});
#else
    return (f2){fminf(fmaxf(v.x, lo), hi), fminf(fmaxf(v.y, lo), hi)};
#endif
}

// stable softplus: max(y,0) + log(1+exp(-|y|))   (setup + once-per-step only)
__device__ __forceinline__ float softplus_fast(float y) {
    float m = fmaxf(y, 0.0f);
    float e = fexp2(-fabsf(y) * LOG2E);
    return fmaf(LN2, flog2(1.0f + e), m);
}

__device__ __forceinline__ float sigmoid_fast(float y) {
    return frcp(1.0f + fexp2(-y * LOG2E));
}

// sum over the 8-lane group (lanes s*8+o, o=0..7): xor1, xor2 (quad_perm),
// then xor7 (row_half_mirror) which equals xor4 once the quad is uniform.
// Pure DPP - no LDS pipe.
__device__ __forceinline__ float oct_sum(float v) {
#if __has_builtin(__builtin_amdgcn_mov_dpp)
    int i = __float_as_int(v);
    v += __int_as_float(__builtin_amdgcn_mov_dpp(i, 0xB1, 0xF, 0xF, true));  // quad_perm 1,0,3,2 (xor1)
    i = __float_as_int(v);
    v += __int_as_float(__builtin_amdgcn_mov_dpp(i, 0x4E, 0xF, 0xF, true));  // quad_perm 2,3,0,1 (xor2)
    i = __float_as_int(v);
    v += __int_as_float(__builtin_amdgcn_mov_dpp(i, 0x141, 0xF, 0xF, true)); // row_half_mirror (xor7)
    return v;
#else
    v += __shfl_xor(v, 1, 64);
    v += __shfl_xor(v, 2, 64);
    v += __shfl_xor(v, 4, 64);
    return v;
#endif
}

__device__ __forceinline__ float fixnum(float v) {
    if (isnan(v)) return 0.0f;
    if (isinf(v)) return v > 0.0f ? 3.4028234663852886e38f : -3.4028234663852886e38f;
    return v;
}

// One wave = 8 sims x 8 unit-slots of ONE batch element (2 waves per b).
// lane = s_local*8 + o: sim s_local (0..7), hidden units j = 16p + o (+8),
// p = 0..3, packed as 4 f2 per weight array -> 40 VGPRs of weights + ~20
// state = fits the 64-VGPR budget the allocator insists on (R3/R4 spilled
// 23 MB/launch at 80 regs demand). No big LDS tile: W1 setup reads are
// L1-resident; LDS is only 256 B of final stats -> no occupancy cap.
__global__ void __launch_bounds__(256) sde_kernel(
    const float* __restrict__ z,  const float* __restrict__ W1,
    const float* __restrict__ b1, const float* __restrict__ W2,
    const float* __restrict__ b2, const float* __restrict__ Wb,
    const float* __restrict__ bb, const float* __restrict__ Wn,
    const float* __restrict__ bn, const float* __restrict__ osc,
    const float* __restrict__ obias, const float* __restrict__ noise,
    float* __restrict__ out)
{
    __shared__ float sm_rt[32];
    __shared__ float sm_ec[32];

    const int lane = threadIdx.x & 63;
    const int wv = threadIdx.x >> 6;      // 0..3
    const int b_local = wv >> 1;          // 0..1
    const int b = blockIdx.x * 2 + b_local;
    const int o = lane & 7;               // unit-slot 0..7
    const int s = ((wv & 1) << 3) | (lane >> 3);  // sim 0..15

    const float* zr = z + (size_t)b * SDE_L;

    // --- setup: lane l computes zW1 entry for hidden unit j = l ---
    // W1 row read from global: 33 KB working set, L1-resident.
    float accz = b1[lane];
    {
        const float* wrow = W1 + lane * 130 + 2;
        #pragma unroll
        for (int m = 0; m < SDE_L; m += 2) {
            float2 w = *(const float2*)(wrow + m);   // 8B-aligned (520*l + 8 + 8m)
            accz = fmaf(zr[m], w.x, accz);
            accz = fmaf(zr[m + 1], w.y, accz);
        }
    }

    // --- boundary / ndt: 128-dot reduced over the wave ---
    float zb0 = zr[2 * lane], zb1 = zr[2 * lane + 1];
    float pb = fmaf(zb0, Wb[2 * lane], zb1 * Wb[2 * lane + 1]);
    float pn = fmaf(zb0, Wn[2 * lane], zb1 * Wn[2 * lane + 1]);
    #pragma unroll
    for (int off = 32; off > 0; off >>= 1) {
        pb += __shfl_xor(pb, off, 64);
        pn += __shfl_xor(pn, off, 64);
    }
    const float half_b = 0.5f * (softplus_fast(pb + bb[0]) + 0.3f);
    const float ndt = softplus_fast(pn + bn[0]) + 0.05f;

    // --- this lane's 8 hidden units: j = 16p + o and 16p + 8 + o ---
    f2 zw2[4], w1x2[4], w1t2[4], w2a2[4], w2b2[4];
    #pragma unroll
    for (int p = 0; p < 4; ++p) {
        int j0 = 16 * p + o, j1 = j0 + 8;
        zw2[p] = (f2){__shfl(accz, j0, 64), __shfl(accz, j1, 64)};
        float2 wa = *(const float2*)(W1 + j0 * 130);  // {w1x, w1t}
        float2 wb = *(const float2*)(W1 + j1 * 130);
        w1x2[p] = (f2){wa.x, wb.x};
        w1t2[p] = (f2){wa.y, wb.y};
        w2a2[p] = (f2){W2[j0], W2[j1]};
        w2b2[p] = (f2){W2[64 + j0], W2[64 + j1]};
    }

    const float b20 = b2[0], b21 = b2[1];
    const float* nzp = noise + (size_t)b * SDE_S + s;
    const f2 c105 = (f2){105.0f, 105.0f};
    const f2 c945 = (f2){945.0f, 945.0f};
    const f2 c15  = (f2){15.0f, 15.0f};
    const f2 c420 = (f2){420.0f, 420.0f};

    float x = 0.0f, surv = 1.0f, ert = 0.0f, ecorr = 0.0f;
    float t = 0.0f;

    for (int k = 0; k < SDE_STEPS; ++k) {
        float nz = *nzp;                 // issued early; first use is ~100 insts later
        nzp += SDE_B * SDE_S;

        f2 x2 = (f2){x, x}, t2 = (f2){t, t};
        f2 A0 = (f2){0.0f, 0.0f}, A1 = (f2){0.0f, 0.0f};
        #pragma unroll
        for (int g = 0; g < 2; ++g) {
            f2 pre0 = ffma2(x2, w1x2[2 * g],     ffma2(t2, w1t2[2 * g],     zw2[2 * g]));
            f2 pre1 = ffma2(x2, w1x2[2 * g + 1], ffma2(t2, w1t2[2 * g + 1], zw2[2 * g + 1]));
            // Pade [5/4] tanh, input clamped to +-3.8 (max err ~1.4e-3)
            pre0 = fclamp2(pre0, -3.8f, 3.8f);
            pre1 = fclamp2(pre1, -3.8f, 3.8f);
            f2 tt0 = pre0 * pre0, tt1 = pre1 * pre1;
            f2 num0 = pre0 * ffma2(tt0, tt0 + c105, c945);
            f2 num1 = pre1 * ffma2(tt1, tt1 + c105, c945);
            f2 den0 = ffma2(tt0, ffma2(tt0, c15, c420), c945);
            f2 den1 = ffma2(tt1, ffma2(tt1, c15, c420), c945);
            // one rcp serves 4 divisions
            f2 den0s = __builtin_shufflevector(den0, den0, 1, 0);
            f2 den1s = __builtin_shufflevector(den1, den1, 1, 0);
            float p01 = den0.x * den0.y;
            float p23 = den1.x * den1.y;
            float r = frcp(p01 * p23);
            float r01 = r * p23, r23 = r * p01;
            f2 h0 = (num0 * den0s) * (f2){r01, r01};
            f2 h1 = (num1 * den1s) * (f2){r23, r23};
            A0 = ffma2(h0, w2a2[2 * g], ffma2(h1, w2a2[2 * g + 1], A0));
            A1 = ffma2(h0, w2b2[2 * g], ffma2(h1, w2b2[2 * g + 1], A1));
        }
        float a0 = oct_sum(A0.x + A0.y);
        float a1 = oct_sum(A1.x + A1.y);
        // identical on all 8 lanes of the sim-group -> state stays consistent
        float drift = fminf(fmaxf(a0 + b20, -5.0f), 5.0f);
        float diff = softplus_fast(a1 + b21) + 0.1f;
        x = fmaf(drift, SDE_DT, fmaf(diff * SDE_SQRT_DT, nz, x));
        x = fminf(fmaxf(x, -10.0f), 10.0f);
        float dist = fabsf(x) - half_b;
        float hz = fminf(sigmoid_fast(SDE_TEMP * dist), 0.99f);
        float cross = surv * hz;
        surv = surv * (1.0f - hz);      // == exp(sum log1p(-hz)) to fp32 rounding
        t += SDE_DT;                    // t is now (k+1)*DT
        ert = fmaf(cross, t, ert);
        ecorr += (x > 0.0f) ? cross : 0.0f;
    }

    ert += surv;                    // * (STEPS*DT) = 1.0
    ecorr = fmaf(surv, 0.5f, ecorr);
    float rt = ert + ndt;           // seconds; x1000 applied after stats

    // --- combine the b's two waves: stash per-sim results in LDS ---
    if (o == 0) {
        sm_rt[b_local * 16 + s] = rt;
        sm_ec[b_local * 16 + s] = ecorr;
    }
    __syncthreads();

    if ((wv & 1) == 0 && lane < 16) {
        float v = sm_rt[b_local * 16 + lane];
        float e = sm_ec[b_local * 16 + lane];
        float sum = v, se = e;
        #pragma unroll
        for (int off = 8; off > 0; off >>= 1) {   // lanes 0..15: stays in-group
            sum += __shfl_xor(sum, off, 64);
            se += __shfl_xor(se, off, 64);
        }
        float mean = sum * (1.0f / 16.0f);
        float d = v - mean;
        float vv = d * d;
        #pragma unroll
        for (int off = 8; off > 0; off >>= 1) vv += __shfl_xor(vv, off, 64);

        if (lane == 0) {
            float std_ms = sqrtf(vv * (1.0f / 15.0f)) * 1000.0f + 0.001f;
            float o0 = fmaf(mean * 1000.0f, osc[0], obias[0]);
            float o1 = fmaf(std_ms, osc[1], obias[1]);
            float o2 = fmaf(se * (1.0f / 16.0f), osc[2], obias[2]);
            out[b * 3 + 0] = fixnum(o0);
            out[b * 3 + 1] = fixnum(o1);
            out[b * 3 + 2] = fixnum(o2);
        }
    }
}

extern "C" void kernel_launch(void* const* d_in, const int* in_sizes, int n_in,
                              void* d_out, int out_size, void* d_ws, size_t ws_size,
                              hipStream_t stream) {
    const float* z     = (const float*)d_in[0];
    const float* W1    = (const float*)d_in[1];
    const float* b1    = (const float*)d_in[2];
    const float* W2    = (const float*)d_in[3];
    const float* b2    = (const float*)d_in[4];
    const float* Wb    = (const float*)d_in[5];
    const float* bb    = (const float*)d_in[6];
    const float* Wn    = (const float*)d_in[7];
    const float* bn    = (const float*)d_in[8];
    const float* osc   = (const float*)d_in[9];
    const float* obias = (const float*)d_in[10];
    const float* noise = (const float*)d_in[11];
    float* out = (float*)d_out;

    dim3 grid(SDE_B / 2), block(256);
    sde_kernel<<<grid, block, 0, stream>>>(z, W1, b1, W2, b2, Wb, bb, Wn, bn,
                                           osc, obias, noise, out);
}

// Round 6
// 353.257 us; speedup vs baseline: 1.2209x; 1.2209x over previous
//
#include <hip/hip_runtime.h>
#include <hip/hip_fp16.h>
#include <math.h>

#define SDE_B 16384
#define SDE_S 16
#define SDE_STEPS 50
#define SDE_L 128
#define SDE_DT 0.02f
#define SDE_SQRT_DT 0.14142135623730951f
#define SDE_TEMP 20.0f
#define LOG2E 1.44269504088896340736f
#define LN2 0.69314718055994530942f
#define SC2 (2.0f * LOG2E)          /* pre-scale so tanh arg feeds exp2 directly */
#define CT (SDE_TEMP * LOG2E)       /* hazard arg scale */

#if __has_builtin(__builtin_amdgcn_exp2f)
__device__ __forceinline__ float fexp2(float x) { return __builtin_amdgcn_exp2f(x); }
#else
__device__ __forceinline__ float fexp2(float x) { return __exp2f(x); }
#endif

#if __has_builtin(__builtin_amdgcn_logf)
__device__ __forceinline__ float flog2(float x) { return __builtin_amdgcn_logf(x); }
#else
__device__ __forceinline__ float flog2(float x) { return __log2f(x); }
#endif

#if __has_builtin(__builtin_amdgcn_rcpf)
__device__ __forceinline__ float frcp(float x) { return __builtin_amdgcn_rcpf(x); }
#else
__device__ __forceinline__ float frcp(float x) { return 1.0f / x; }
#endif

// extract one f16 from a half2 as float; constant `hi` folds; feeding fmaf()
// lets clang form v_fma_mix_f32 (full-rate, no cvt inst).
__device__ __forceinline__ float hsel(__half2 h, int hi) {
    return __half2float(hi ? __high2half(h) : __low2half(h));
}

// stable softplus: max(y,0) + log(1+exp(-|y|))
__device__ __forceinline__ float softplus_fast(float y) {
    float m = fmaxf(y, 0.0f);
    float e = fexp2(-fabsf(y) * LOG2E);
    return fmaf(LN2, flog2(1.0f + e), m);
}

// sum over the 4-lane quad (lanes grouped as sim*4+q) via DPP quad_perm
__device__ __forceinline__ float quad_sum(float v) {
#if __has_builtin(__builtin_amdgcn_mov_dpp)
    int i = __float_as_int(v);
    v += __int_as_float(__builtin_amdgcn_mov_dpp(i, 0xB1, 0xF, 0xF, true)); // xor 1
    i = __float_as_int(v);
    v += __int_as_float(__builtin_amdgcn_mov_dpp(i, 0x4E, 0xF, 0xF, true)); // xor 2
    return v;
#else
    v += __shfl_xor(v, 1, 64);
    v += __shfl_xor(v, 2, 64);
    return v;
#endif
}

__device__ __forceinline__ float fixnum(float v) {
    if (isnan(v)) return 0.0f;
    if (isinf(v)) return v > 0.0f ? 3.4028234663852886e38f : -3.4028234663852886e38f;
    return v;
}

// One wave per batch element b. 64 lanes = 16 sims x 4 hidden-quarters.
// lane = s*4 + q: sim s, hidden units j = 4*i + q, i in [0,16).
// All weights f16-packed (half2) -> 40 VGPRs; total demand ~58 fits the
// allocator's 64-VGPR budget (R3/R4: 80-float demand spilled 23 MB/launch).
// tanh(p) = 1 - 2/(1+exp2(p*2log2e)): weights/zw pre-scaled by 2log2e,
// "1 - 2*" folded into w2' = -2*w2 with sum(w2) added once at setup.
__global__ void __launch_bounds__(256) sde_kernel(
    const float* __restrict__ z,  const float* __restrict__ W1,
    const float* __restrict__ b1, const float* __restrict__ W2,
    const float* __restrict__ b2, const float* __restrict__ Wb,
    const float* __restrict__ bb, const float* __restrict__ Wn,
    const float* __restrict__ bn, const float* __restrict__ osc,
    const float* __restrict__ obias, const float* __restrict__ noise,
    float* __restrict__ out)
{
    const int lane = threadIdx.x & 63;
    const int wv = threadIdx.x >> 6;
    const int b = blockIdx.x * 4 + wv;
    const int s = lane >> 2;
    const int q = lane & 3;

    const float* zr = z + (size_t)b * SDE_L;

    // --- setup: lane l computes zW1 entry for hidden unit j = l ---
    float accz = b1[lane];
    {
        const float* wrow = W1 + lane * 130 + 2;
        #pragma unroll
        for (int m = 0; m < SDE_L; m += 2) {
            float2 w = *(const float2*)(wrow + m);
            accz = fmaf(zr[m], w.x, accz);
            accz = fmaf(zr[m + 1], w.y, accz);
        }
    }
    accz *= SC2;   // pre-scaled for exp2-tanh

    // --- boundary / ndt: 128-dot reduced over the wave ---
    float zb0 = zr[2 * lane], zb1 = zr[2 * lane + 1];
    float pb = fmaf(zb0, Wb[2 * lane], zb1 * Wb[2 * lane + 1]);
    float pn = fmaf(zb0, Wn[2 * lane], zb1 * Wn[2 * lane + 1]);
    #pragma unroll
    for (int off = 32; off > 0; off >>= 1) {
        pb += __shfl_xor(pb, off, 64);
        pn += __shfl_xor(pn, off, 64);
    }
    const float half_b = 0.5f * (softplus_fast(pb + bb[0]) + 0.3f);
    const float ndt = softplus_fast(pn + bn[0]) + 0.05f;
    const float Hh = CT * half_b;   // hazard arg offset (folded TEMP*log2e)

    // --- pack this lane's 16 hidden units (j = 4i+q) as f16 half2 pairs ---
    __half2 zwh[8], wxh[8], wth[8], wah[8], wbh[8];
    float S2a = 0.0f, S2b = 0.0f;
    #pragma unroll
    for (int p = 0; p < 8; ++p) {
        int j0 = 4 * (2 * p) + q, j1 = 4 * (2 * p + 1) + q;
        float zw0 = __shfl(accz, j0, 64), zw1 = __shfl(accz, j1, 64);
        zwh[p] = __halves2half2(__float2half_rn(zw0), __float2half_rn(zw1));
        float2 wa0 = *(const float2*)(W1 + j0 * 130);  // {w1x, w1t}
        float2 wa1 = *(const float2*)(W1 + j1 * 130);
        wxh[p] = __halves2half2(__float2half_rn(wa0.x * SC2), __float2half_rn(wa1.x * SC2));
        wth[p] = __halves2half2(__float2half_rn(wa0.y * SC2), __float2half_rn(wa1.y * SC2));
        float a0w = W2[j0], a1w = W2[j1];
        float b0w = W2[64 + j0], b1w = W2[64 + j1];
        S2a += a0w + a1w;
        S2b += b0w + b1w;
        wah[p] = __halves2half2(__float2half_rn(-2.0f * a0w), __float2half_rn(-2.0f * a1w));
        wbh[p] = __halves2half2(__float2half_rn(-2.0f * b0w), __float2half_rn(-2.0f * b1w));
    }
    // per-lane accumulator bases: quad-sum over 4 lanes yields b2 + full sums
    const float a0base = fmaf(0.25f, b2[0], S2a);
    const float a1base = fmaf(0.25f, b2[1], S2b);

    const float* nzp = noise + (size_t)b * SDE_S + s;

    float x = 0.0f, surv = 1.0f, ert = 0.0f, ecorr = 0.0f;
    float t = 0.0f;

    for (int k = 0; k < SDE_STEPS; ++k) {
        float nzs = (*nzp) * SDE_SQRT_DT;
        nzp += SDE_B * SDE_S;

        float a0 = a0base, a1 = a1base;
        #pragma unroll
        for (int g = 0; g < 4; ++g) {
            // 4 units: i = 4g..4g+3 -> pairs p = 2g (lo,hi), 2g+1 (lo,hi)
            float d0, d1, d2, d3;
            {
                float pr0 = fmaf(x, hsel(wxh[2*g], 0), fmaf(t, hsel(wth[2*g], 0), hsel(zwh[2*g], 0)));
                float pr1 = fmaf(x, hsel(wxh[2*g], 1), fmaf(t, hsel(wth[2*g], 1), hsel(zwh[2*g], 1)));
                float pr2 = fmaf(x, hsel(wxh[2*g+1], 0), fmaf(t, hsel(wth[2*g+1], 0), hsel(zwh[2*g+1], 0)));
                float pr3 = fmaf(x, hsel(wxh[2*g+1], 1), fmaf(t, hsel(wth[2*g+1], 1), hsel(zwh[2*g+1], 1)));
                d0 = fexp2(pr0) + 1.0f;
                d1 = fexp2(pr1) + 1.0f;
                d2 = fexp2(pr2) + 1.0f;
                d3 = fexp2(pr3) + 1.0f;
            }
            // one rcp serves 4 reciprocals: g_i = 1/d_i
            float p01 = d0 * d1, p23 = d2 * d3;
            float r = frcp(p01 * p23);
            float r01 = r * p23, r23 = r * p01;
            float g0 = r01 * d1, g1 = r01 * d0;
            float g2 = r23 * d3, g3 = r23 * d2;
            // h_i = 1 - 2*g_i folded: a += g_i * (-2*w2); base carries sum(w2)
            a0 = fmaf(g0, hsel(wah[2*g], 0), a0);
            a1 = fmaf(g0, hsel(wbh[2*g], 0), a1);
            a0 = fmaf(g1, hsel(wah[2*g], 1), a0);
            a1 = fmaf(g1, hsel(wbh[2*g], 1), a1);
            a0 = fmaf(g2, hsel(wah[2*g+1], 0), a0);
            a1 = fmaf(g2, hsel(wbh[2*g+1], 0), a1);
            a0 = fmaf(g3, hsel(wah[2*g+1], 1), a0);
            a1 = fmaf(g3, hsel(wbh[2*g+1], 1), a1);
        }
        a0 = quad_sum(a0);
        a1 = quad_sum(a1);
        // identical on all 4 lanes of the quad -> state stays consistent
        float drift = fminf(fmaxf(a0, -5.0f), 5.0f);
        float diff = softplus_fast(a1) + 0.1f;
        x = fmaf(drift, SDE_DT, fmaf(diff, nzs, x));
        x = fminf(fmaxf(x, -10.0f), 10.0f);
        // hz = sigmoid(TEMP*(|x|-half_b)) = 1/(1+exp2(Hh - CT*|x|))
        float e = fexp2(fmaf(fabsf(x), -CT, Hh));
        float hz = fminf(frcp(1.0f + e), 0.99f);
        float cross = surv * hz;
        surv = surv * (1.0f - hz);
        t += SDE_DT;                    // t is now (k+1)*DT
        ert = fmaf(cross, t, ert);
        ecorr += (x > 0.0f) ? cross : 0.0f;
    }

    ert += surv;                    // * (STEPS*DT) = 1.0
    ecorr = fmaf(surv, 0.5f, ecorr);
    float rt = ert + ndt;           // seconds; x1000 applied after stats

    // --- stats over 16 sims (mask quad-redundant copies to q==0) ---
    float sr = (q == 0) ? rt : 0.0f;
    float scr = (q == 0) ? ecorr : 0.0f;
    #pragma unroll
    for (int off = 32; off > 0; off >>= 1) {
        sr += __shfl_xor(sr, off, 64);
        scr += __shfl_xor(scr, off, 64);
    }
    float mean = sr * (1.0f / 16.0f);
    float d = rt - mean;
    float vv = (q == 0) ? d * d : 0.0f;
    #pragma unroll
    for (int off = 32; off > 0; off >>= 1) vv += __shfl_xor(vv, off, 64);

    if (lane == 0) {
        float std_ms = sqrtf(vv * (1.0f / 15.0f)) * 1000.0f + 0.001f;
        float o0 = fmaf(mean * 1000.0f, osc[0], obias[0]);
        float o1 = fmaf(std_ms, osc[1], obias[1]);
        float o2 = fmaf(scr * (1.0f / 16.0f), osc[2], obias[2]);
        out[b * 3 + 0] = fixnum(o0);
        out[b * 3 + 1] = fixnum(o1);
        out[b * 3 + 2] = fixnum(o2);
    }
}

extern "C" void kernel_launch(void* const* d_in, const int* in_sizes, int n_in,
                              void* d_out, int out_size, void* d_ws, size_t ws_size,
                              hipStream_t stream) {
    const float* z     = (const float*)d_in[0];
    const float* W1    = (const float*)d_in[1];
    const float* b1    = (const float*)d_in[2];
    const float* W2    = (const float*)d_in[3];
    const float* b2    = (const float*)d_in[4];
    const float* Wb    = (const float*)d_in[5];
    const float* bb    = (const float*)d_in[6];
    const float* Wn    = (const float*)d_in[7];
    const float* bn    = (const float*)d_in[8];
    const float* osc   = (const float*)d_in[9];
    const float* obias = (const float*)d_in[10];
    const float* noise = (const float*)d_in[11];
    float* out = (float*)d_out;

    dim3 grid(SDE_B / 4), block(256);
    sde_kernel<<<grid, block, 0, stream>>>(z, W1, b1, W2, b2, Wb, bb, Wn, bn,
                                           osc, obias, noise, out);
}